// Round 3
// baseline (172.819 us; speedup 1.0000x reference)
//
#include <hip/hip_runtime.h>

// VectorQuantizer: x (32,64,64,64) f32, codebook (1024,64) f32
// out = concat( quantized (32,64,64,64) f32 , indices (32,64,64) as f32 )
//
// R9 = R8's VERIFIED int-key exact math, re-geometried for occupancy.
//  - R8 post-mortem: main 70us, MfmaUtil 30 / VALU 49 / Occ 30.8 -> issue-
//    starved at 4 waves/SIMD (grid 1024 = 4 blocks/CU, LDS 37.9KB). VGPR was
//    56 -> room for 8 waves/SIMD if LDS/block < 20KB.
//  - wave = 16 positions (1 M-tile), block = 64 pos, grid 2048 = 8 blocks/CU,
//    __launch_bounds__(256,8) -> target 32 waves/CU, VGPR capped 64.
//  - chunk = 2 ct = 9216B: 8KB B/R stream + 128B cn INTERLEAVED by prep
//    (+pad). cn rides the global_load_lds stage -> no cn_lds, no L2-latency
//    C-init hazard. LDS/block = 2*9216 + 512 = 18.9KB.
//  - acc chain ordered R-terms first then B-terms to cut peak live regs.
//  - numerics bit-identical to R8 (absmax 0): 6-MFMA split scheme, int keys
//    key=(cvt_i32(dist*2048)<<10)|code, EPS_Q=16, exact-f32 rescan.

typedef _Float16 f16x8 __attribute__((ext_vector_type(8)));
typedef float    f32x4 __attribute__((ext_vector_type(4)));

#define VQ_D    64
#define VQ_HW   4096
#define VQ_NPOS 131072
#define SC      2048.0f
#define EPS_Q   16         // flag margin in q-units (16/2048 = 7.8e-3)
#define CHB     9216       // bytes per 2-ct chunk: 8KB B/R + 128B cn + pad
// ws float offsets (bp stream = 32 chunks * 9216B = 294912B = 73728 floats)
#define WS_CBN  73728      // f32 cn[1024]
#define WS_CBT  74752      // float4 cbT4[16384] (256 KB)
#define WS_CNT  140288     // int rescan counter
#define WS_LIST 140292     // int list[131072]

// ---------- prep ----------
// B item: it=(ct*4+s)*64+lane; s: 0=bh2 ks0, 1=bh2 ks1, 2=rb2k ks0, 3=rb2k ks1
// bh2 = -2*f16(b) (exact), rb2k = f16(-2*SC*(b - bh)).
// byte addr = (ct>>1)*CHB + (ct&1)*4096 + s*1024 + lane*16 ; cn for code
// k=ct*16+i at (ct>>1)*CHB + 8192 + (ct&1)*64 + i*4.
__global__ __launch_bounds__(256)
void vq_prep(const float* __restrict__ cb, float* __restrict__ ws)
{
    const int tid = threadIdx.x;
    const int blk = blockIdx.x;
    if (blk < 64) {
        const int it   = blk * 256 + tid;            // [0, 16384)
        const int ct   = it >> 8;
        const int s    = (it >> 6) & 3;
        const int lane = it & 63;
        const int ks   = s & 1, isR = s >> 1;
        const int n    = ct * 16 + (lane & 15);      // code (B column)
        const int k0   = ks * 32 + (lane >> 4) * 8;  // dim  (B row)
        const float* src = cb + n * 64 + k0;
        f16x8 o;
        #pragma unroll
        for (int j = 0; j < 8; ++j) {
            const float b = src[j];
            const _Float16 bh = (_Float16)b;
            o[j] = isR ? (_Float16)((b - (float)bh) * (-2.0f * SC))
                       : (_Float16)(-2.0f * (float)bh);
        }
        *(f16x8*)((char*)ws + (size_t)(ct >> 1) * CHB + (ct & 1) * 4096
                            + s * 1024 + lane * 16) = o;
    } else if (blk < 128) {
        const int it = (blk - 64) * 256 + tid;       // [0, 16384)
        const int k = it >> 4, j4 = it & 15;
        ((float4*)(ws + WS_CBT))[j4 * 1024 + k] = ((const float4*)cb)[it];
    } else {
        const int k = (blk - 128) * 256 + tid;       // [0, 1024)
        const float4* row = (const float4*)(cb + k * 64);
        float a0 = 0.f, a1 = 0.f, a2 = 0.f, a3 = 0.f;
        #pragma unroll
        for (int j = 0; j < 16; ++j) {
            const float4 c = row[j];
            a0 = fmaf(c.x, c.x, a0); a1 = fmaf(c.y, c.y, a1);
            a2 = fmaf(c.z, c.z, a2); a3 = fmaf(c.w, c.w, a3);
        }
        const float cn = (a0 + a1) + (a2 + a3);
        ws[WS_CBN + k] = cn;
        const int ct = k >> 4, i = k & 15;
        *(float*)((char*)ws + (size_t)(ct >> 1) * CHB + 8192
                            + (ct & 1) * 64 + i * 4) = cn;
        if (k == 0) ((int*)ws)[WS_CNT] = 0;
    }
}

// ---------- main ----------
#define GLOAD_LDS(GP, LP)                                                     \
    __builtin_amdgcn_global_load_lds(                                         \
        (const __attribute__((address_space(1))) unsigned int*)(GP),          \
        (__attribute__((address_space(3))) unsigned int*)(LP), 16, 0, 0)

__global__ __launch_bounds__(256, 8)
void vq_main(const float* __restrict__ x,
             const float* __restrict__ cb,
             float* __restrict__ ws,
             float* __restrict__ out,
             float* __restrict__ idx_out)
{
    __shared__ f16x8 bbuf[2][CHB / 16];   // 2 x 9216B chunk (2 ct + cn)
    __shared__ int   sk[64];
    __shared__ int   smg[64];

    const int tid  = threadIdx.x;
    const int lane = tid & 63;
    const int wv   = tid >> 6;        // 4 waves, 16 positions each
    const int m    = lane & 15;
    const int q    = lane >> 4;

    const int p0 = blockIdx.x * 64;   // block: 64 consecutive positions
    const int b  = p0 >> 12;
    const int n0 = p0 & (VQ_HW - 1);
    const float* xw = x + (size_t)b * (VQ_D * VQ_HW) + n0 + wv * 16;

    // stage chunk 0 (latency hidden under A-fragment build); 9 x 1KB wave-ops
    {
        const char* gs = (const char*)ws + lane * 16;
        char*       ld = (char*)&bbuf[0][0];
        for (int o = wv; o < 9; o += 4) GLOAD_LDS(gs + o * 1024, ld + o * 1024);
    }

    // ---- A fragments (hi + scaled residual), 1 M-tile, resident ----
    f16x8 Ah[2], Ra[2];
    #pragma unroll
    for (int ks = 0; ks < 2; ++ks) {
        f16x8 h8, r8;
        #pragma unroll
        for (int j = 0; j < 8; ++j) {
            const float v = xw[(size_t)(ks * 32 + q * 8 + j) * VQ_HW + m];
            const _Float16 vh = (_Float16)v;
            h8[j] = vh;
            r8[j] = (_Float16)((v - (float)vh) * SC);
        }
        Ah[ks] = h8; Ra[ks] = r8;
    }

    int d1[4], d2[4];
    #pragma unroll
    for (int r = 0; r < 4; ++r) { d1[r] = 0x7FFFFFFF; d2[r] = 0x7FFFFFFF; }

    const f32x4 zero4 = {0.f, 0.f, 0.f, 0.f};

    for (int cc = 0; cc < 32; ++cc) {
        __syncthreads();              // chunk cc staged; buf[(cc+1)&1] free
        if (cc < 31) {                // prefetch next chunk into other buffer
            const char* gs = (const char*)ws + (size_t)(cc + 1) * CHB + lane * 16;
            char*       ld = (char*)&bbuf[(cc + 1) & 1][0];
            for (int o = wv; o < 9; o += 4) GLOAD_LDS(gs + o * 1024, ld + o * 1024);
        }
        const char* bufc = (const char*)&bbuf[cc & 1][0];
        #pragma unroll
        for (int ci = 0; ci < 2; ++ci) {
            const int ctg = cc * 2 + ci;
            const f16x8* bp = (const f16x8*)(bufc + ci * 4096);
            // R-terms first (R0/R1 die before B-terms) -> lower peak live regs
            const f16x8 R0 = bp[128 + lane];
            const f16x8 R1 = bp[192 + lane];
            f32x4 acc = __builtin_amdgcn_mfma_f32_16x16x32_f16(Ah[0], R0, zero4, 0,0,0);
            acc       = __builtin_amdgcn_mfma_f32_16x16x32_f16(Ah[1], R1, acc,   0,0,0);
            const f16x8 B0 = bp[lane];
            const f16x8 B1 = bp[64 + lane];
            acc       = __builtin_amdgcn_mfma_f32_16x16x32_f16(Ra[0], B0, acc,   0,0,0);
            acc       = __builtin_amdgcn_mfma_f32_16x16x32_f16(Ra[1], B1, acc,   0,0,0);
            const float cv = *(const float*)(bufc + 8192 + ci * 64 + m * 4);
            const f32x4 Ci = {cv, cv, cv, cv};
            f32x4 acm = __builtin_amdgcn_mfma_f32_16x16x32_f16(Ah[0], B0, Ci,  0,0,0);
            acm       = __builtin_amdgcn_mfma_f32_16x16x32_f16(Ah[1], B1, acm, 0,0,0);
            const int code_ = ctg * 16 + m;
            #pragma unroll
            for (int r = 0; r < 4; ++r) {
                // q-units: dist*2048 = acm*2048 + acc  (SC == 2048)
                const float qf  = fmaf(acm[r], SC, acc[r]);
                const int   key = ((int)qf << 10) | code_;
                const int   t   = (key > d1[r]) ? key : d1[r];
                d2[r] = (t < d2[r]) ? t : d2[r];
                d1[r] = (key < d1[r]) ? key : d1[r];
            }
        }
    }

    // ---- top-2 merge across the 16 code-columns (keys carry the code) ----
    #pragma unroll
    for (int off = 1; off < 16; off <<= 1)
        #pragma unroll
        for (int r = 0; r < 4; ++r) {
            const int od1 = __shfl_xor(d1[r], off, 64);
            const int od2 = __shfl_xor(d2[r], off, 64);
            const int mx  = (d1[r] > od1) ? d1[r] : od1;
            const int mn2 = (d2[r] < od2) ? d2[r] : od2;
            d2[r] = (mx < mn2) ? mx : mn2;
            d1[r] = (d1[r] < od1) ? d1[r] : od1;
        }

    if (m == 0) {
        #pragma unroll
        for (int r = 0; r < 4; ++r) {
            const int li = wv * 16 + q * 4 + r;
            sk[li]  = d1[r] & 1023;
            smg[li] = (d2[r] >> 10) - (d1[r] >> 10);   // gap in q-units
        }
    }
    __syncthreads();

    // ---- epilogue: indices, rescan flags, quantized scatter ----
    const int pos  = tid & 63;
    const int part = tid >> 6;        // 4 threads per position, 16 dims each
    const int bk   = sk[pos];
    if (part == 0) {
        idx_out[p0 + pos] = (float)bk;
        if (smg[pos] < EPS_Q) {
            const int slot = atomicAdd((int*)ws + WS_CNT, 1);
            ((int*)ws)[WS_LIST + slot] = p0 + pos;
        }
    }
    const float4* cr = (const float4*)(cb + (size_t)bk * VQ_D) + part * 4;
    float* ob = out + (size_t)b * (VQ_D * VQ_HW) + (size_t)(part * 16) * VQ_HW + n0 + pos;
    #pragma unroll
    for (int d4 = 0; d4 < 4; ++d4) {
        const float4 v = cr[d4];
        ob[(size_t)(d4 * 4 + 0) * VQ_HW] = v.x;
        ob[(size_t)(d4 * 4 + 1) * VQ_HW] = v.y;
        ob[(size_t)(d4 * 4 + 2) * VQ_HW] = v.z;
        ob[(size_t)(d4 * 4 + 3) * VQ_HW] = v.w;
    }
}

// ---------- rescan: exact f32 argmin for flagged positions (verified) ----------
__global__ __launch_bounds__(64)
void vq_rescan(const float* __restrict__ x,
               const float* __restrict__ cb,
               const float* __restrict__ ws,
               float* __restrict__ out,
               float* __restrict__ idx_out)
{
    __shared__ float xs[VQ_D];
    const int lane = threadIdx.x;
    const int cnt  = ((const int*)ws)[WS_CNT];
    const int* list = (const int*)ws + WS_LIST;
    const float*  cnb  = ws + WS_CBN;
    const float4* cbT4 = (const float4*)(ws + WS_CBT);

    for (int i = blockIdx.x; i < cnt; i += gridDim.x) {
        const int p = list[i];
        const int b = p >> 12, n = p & (VQ_HW - 1);
        xs[lane] = x[(size_t)b * (VQ_D * VQ_HW) + (size_t)lane * VQ_HW + n];
        __syncthreads();
        float4 xr[16];
        #pragma unroll
        for (int j = 0; j < 16; ++j) xr[j] = ((const float4*)xs)[j];

        float bd = 3.4e38f; int bk = 0;
        #pragma unroll 4
        for (int t = 0; t < 16; ++t) {
            const int code = t * 64 + lane;           // per-lane ascending
            float a0 = 0.f, a1 = 0.f, a2 = 0.f, a3 = 0.f;
            #pragma unroll
            for (int j4 = 0; j4 < 16; ++j4) {
                const float4 c = cbT4[j4 * 1024 + code];   // coalesced
                a0 = fmaf(xr[j4].x, c.x, a0); a1 = fmaf(xr[j4].y, c.y, a1);
                a2 = fmaf(xr[j4].z, c.z, a2); a3 = fmaf(xr[j4].w, c.w, a3);
            }
            const float dist = fmaf(-2.0f, (a0 + a1) + (a2 + a3), cnb[code]);
            if (dist < bd) { bd = dist; bk = code; }
        }
        #pragma unroll
        for (int off = 1; off < 64; off <<= 1) {      // min dist, tie -> min k
            const float od = __shfl_xor(bd, off, 64);
            const int   ok = __shfl_xor(bk, off, 64);
            if (od < bd || (od == bd && ok < bk)) { bd = od; bk = ok; }
        }
        out[(size_t)b * (VQ_D * VQ_HW) + (size_t)lane * VQ_HW + n] = cb[(size_t)bk * VQ_D + lane];
        if (lane == 0) idx_out[p] = (float)bk;
        __syncthreads();
    }
}

extern "C" void kernel_launch(void* const* d_in, const int* in_sizes, int n_in,
                              void* d_out, int out_size, void* d_ws, size_t ws_size,
                              hipStream_t stream) {
    const float* x  = (const float*)d_in[0];
    const float* cb = (const float*)d_in[1];
    float* out = (float*)d_out;
    float* idx = out + (size_t)VQ_NPOS * VQ_D;   // 8,388,608 floats in
    float* ws  = (float*)d_ws;                    // ~1.09 MB used

    vq_prep  <<<dim3(132),  dim3(256), 0, stream>>>(cb, ws);
    vq_main  <<<dim3(2048), dim3(256), 0, stream>>>(x, cb, ws, out, idx);
    vq_rescan<<<dim3(1024), dim3(64),  0, stream>>>(x, cb, ws, out, idx);
}

// Round 4
// 156.403 us; speedup vs baseline: 1.1050x; 1.1050x over previous
//
#include <hip/hip_runtime.h>

// VectorQuantizer: x (32,64,64,64) f32, codebook (1024,64) f32
// out = concat( quantized (32,64,64,64) f32 , indices (32,64,64) as f32 )
//
// R10 = R8 geometry (2 M-tiles/wave, 16 waves/CU) + VALU diet.
//  - R9 post-mortem: doubling occupancy (58.6%) made main SLOWER (70->76us)
//    because 16-pos waves double LDS read traffic/position (~46% LDS busy).
//    Not occupancy-bound: issue-mix bound (VALU 54 + LDS 46 + MFMA 29).
//  - Single 6-MFMA chain in q-units: third A-fragment Ak = 2048*f16(x)
//    (power-of-2 scale = EXACT in f16), C-init = 2048*cn staged in-stream.
//    Removes acm accumulators + the per-r fmaf. Extra f32 accum rounding
//    <= ~1 q-unit -> EPS_Q 16 -> 20 (2*err ~ 14 < 20; flags stay ~100s).
//  - key update = cvt_i32 + lshl_or + v_med3_i32 (asm; valid under d1<=d2
//    invariant) + min = 4 VALU (was ~7 incl. fmaf).
//  - 4-ct chunks (16640B), dbuf + 1KB pad (exec-mask insurance for the
//    lane<16 cn gload) = 36.4KB LDS -> 4 blocks/CU, grid 1024.
//  - manual 2-chunk unroll: all ds_read offsets are compile-time immediates
//    off one base+lane*16 register -> ~zero per-ct address VALU.
//  - exact-f32 rescan path unchanged (verified R6/R8/R9, absmax 0).

typedef _Float16 f16x8 __attribute__((ext_vector_type(8)));
typedef float    f32x4 __attribute__((ext_vector_type(4)));

#define VQ_D    64
#define VQ_HW   4096
#define VQ_NPOS 131072
#define SC      2048.0f
#define EPS_Q   20         // flag margin in q-units (20/2048 = 9.8e-3)
#define CHB     16640      // bytes per 4-ct chunk: 16KB B/R + 256B cn_q
#define CHBP    17664      // LDS buffer stride (CHB + 1KB pad)
// ws float offsets (stream = 16 chunks * 16640B = 266240B = 66560 floats)
#define WS_CBN  66560      // f32 cn[1024] (raw, for rescan)
#define WS_CBT  67584      // float4 cbT4[16384] (256 KB)
#define WS_CNT  133120     // int rescan counter
#define WS_LIST 133124     // int list[131072]

// ---------- prep ----------
// B item: it=(ct*4+s)*64+lane; s: 0=bh2 ks0, 1=bh2 ks1, 2=rb2k ks0, 3=rb2k ks1
// bh2 = -2*f16(b) (exact), rb2k = f16(-2*SC*(b - bh)).
// stream byte addr = (ct>>2)*CHB + (ct&3)*4096 + s*1024 + lane*16
// cn_q for code k=ct*16+i at (ct>>2)*CHB + 16384 + (ct&3)*64 + i*4 (=2048*cn)
__global__ __launch_bounds__(256)
void vq_prep(const float* __restrict__ cb, float* __restrict__ ws)
{
    const int tid = threadIdx.x;
    const int blk = blockIdx.x;
    if (blk < 64) {
        const int it   = blk * 256 + tid;            // [0, 16384)
        const int ct   = it >> 8;
        const int s    = (it >> 6) & 3;
        const int lane = it & 63;
        const int ks   = s & 1, isR = s >> 1;
        const int n    = ct * 16 + (lane & 15);      // code (B column)
        const int k0   = ks * 32 + (lane >> 4) * 8;  // dim  (B row)
        const float* src = cb + n * 64 + k0;
        f16x8 o;
        #pragma unroll
        for (int j = 0; j < 8; ++j) {
            const float b = src[j];
            const _Float16 bh = (_Float16)b;
            o[j] = isR ? (_Float16)((b - (float)bh) * (-2.0f * SC))
                       : (_Float16)(-2.0f * (float)bh);
        }
        *(f16x8*)((char*)ws + (size_t)(ct >> 2) * CHB + (ct & 3) * 4096
                            + s * 1024 + lane * 16) = o;
    } else if (blk < 128) {
        const int it = (blk - 64) * 256 + tid;       // [0, 16384)
        const int k = it >> 4, j4 = it & 15;
        ((float4*)(ws + WS_CBT))[j4 * 1024 + k] = ((const float4*)cb)[it];
    } else {
        const int k = (blk - 128) * 256 + tid;       // [0, 1024)
        const float4* row = (const float4*)(cb + k * 64);
        float a0 = 0.f, a1 = 0.f, a2 = 0.f, a3 = 0.f;
        #pragma unroll
        for (int j = 0; j < 16; ++j) {
            const float4 c = row[j];
            a0 = fmaf(c.x, c.x, a0); a1 = fmaf(c.y, c.y, a1);
            a2 = fmaf(c.z, c.z, a2); a3 = fmaf(c.w, c.w, a3);
        }
        const float cn = (a0 + a1) + (a2 + a3);
        ws[WS_CBN + k] = cn;                         // raw (rescan)
        const int ct = k >> 4, i = k & 15;
        *(float*)((char*)ws + (size_t)(ct >> 2) * CHB + 16384
                            + (ct & 3) * 64 + i * 4) = cn * 2048.0f;  // q-units
        if (k == 0) ((int*)ws)[WS_CNT] = 0;
    }
}

// ---------- main ----------
#define GLOAD_LDS(GP, LP)                                                     \
    __builtin_amdgcn_global_load_lds(                                         \
        (const __attribute__((address_space(1))) unsigned int*)(GP),          \
        (__attribute__((address_space(3))) unsigned int*)(LP), 16, 0, 0)

// stage one 16640B chunk at global GS (per-lane: +lane*16) into LDS at BOFF
#define STAGE(GS, BOFF)                                                       \
    {                                                                         \
        char* ld_ = (char*)bbuf + (BOFF) + wv * 1024;                         \
        const char* gs_ = (GS) + wv * 1024;                                   \
        GLOAD_LDS(gs_,         ld_);                                          \
        GLOAD_LDS(gs_ + 4096,  ld_ + 4096);                                   \
        GLOAD_LDS(gs_ + 8192,  ld_ + 8192);                                   \
        GLOAD_LDS(gs_ + 12288, ld_ + 12288);                                  \
        if (wv == 0 && lane < 16)                                             \
            GLOAD_LDS((GS) + 16384, (char*)bbuf + (BOFF) + 16384);            \
    }

// one 16-code tile: 6-MFMA single chain per M-tile, 4-VALU key updates
#define CT_BODY(BOFF, SLOT, CTG)                                              \
    {                                                                         \
        const f16x8 B0 = *(const f16x8*)(lp + (BOFF) + (SLOT) * 4096);        \
        const f16x8 B1 = *(const f16x8*)(lp + (BOFF) + (SLOT) * 4096 + 1024); \
        const f16x8 R0 = *(const f16x8*)(lp + (BOFF) + (SLOT) * 4096 + 2048); \
        const f16x8 R1 = *(const f16x8*)(lp + (BOFF) + (SLOT) * 4096 + 3072); \
        const float cvq = *(const float*)(cp + (BOFF) + (SLOT) * 64);         \
        const f32x4 Ci = {cvq, cvq, cvq, cvq};                                \
        f32x4 a0 = __builtin_amdgcn_mfma_f32_16x16x32_f16(Ra[0][0], B0, Ci, 0,0,0); \
        f32x4 a1 = __builtin_amdgcn_mfma_f32_16x16x32_f16(Ra[1][0], B0, Ci, 0,0,0); \
        a0 = __builtin_amdgcn_mfma_f32_16x16x32_f16(Ra[0][1], B1, a0, 0,0,0); \
        a1 = __builtin_amdgcn_mfma_f32_16x16x32_f16(Ra[1][1], B1, a1, 0,0,0); \
        a0 = __builtin_amdgcn_mfma_f32_16x16x32_f16(Ah[0][0], R0, a0, 0,0,0); \
        a1 = __builtin_amdgcn_mfma_f32_16x16x32_f16(Ah[1][0], R0, a1, 0,0,0); \
        a0 = __builtin_amdgcn_mfma_f32_16x16x32_f16(Ah[0][1], R1, a0, 0,0,0); \
        a1 = __builtin_amdgcn_mfma_f32_16x16x32_f16(Ah[1][1], R1, a1, 0,0,0); \
        a0 = __builtin_amdgcn_mfma_f32_16x16x32_f16(Ak[0][0], B0, a0, 0,0,0); \
        a1 = __builtin_amdgcn_mfma_f32_16x16x32_f16(Ak[1][0], B0, a1, 0,0,0); \
        a0 = __builtin_amdgcn_mfma_f32_16x16x32_f16(Ak[0][1], B1, a0, 0,0,0); \
        a1 = __builtin_amdgcn_mfma_f32_16x16x32_f16(Ak[1][1], B1, a1, 0,0,0); \
        const int cbase_ = (CTG) * 16 + m;                                    \
        _Pragma("unroll")                                                     \
        for (int r = 0; r < 4; ++r) {                                         \
            const int k0_ = ((int)a0[r] << 10) | cbase_;                      \
            int m0_;                                                          \
            asm("v_med3_i32 %0, %1, %2, %3"                                   \
                : "=v"(m0_) : "v"(k0_), "v"(d1[0][r]), "v"(d2[0][r]));        \
            d2[0][r] = m0_;                                                   \
            d1[0][r] = (k0_ < d1[0][r]) ? k0_ : d1[0][r];                     \
            const int k1_ = ((int)a1[r] << 10) | cbase_;                      \
            int m1_;                                                          \
            asm("v_med3_i32 %0, %1, %2, %3"                                   \
                : "=v"(m1_) : "v"(k1_), "v"(d1[1][r]), "v"(d2[1][r]));        \
            d2[1][r] = m1_;                                                   \
            d1[1][r] = (k1_ < d1[1][r]) ? k1_ : d1[1][r];                     \
        }                                                                     \
    }

__global__ __launch_bounds__(256, 4)
void vq_main(const float* __restrict__ x,
             const float* __restrict__ cb,
             float* __restrict__ ws,
             float* __restrict__ out,
             float* __restrict__ idx_out)
{
    __shared__ f16x8 bbuf[2 * (CHBP / 16)];   // 2 padded 16.6KB chunks
    __shared__ int   sk[128];
    __shared__ int   smg[128];

    const int tid  = threadIdx.x;
    const int lane = tid & 63;
    const int wv   = tid >> 6;        // 4 waves, 32 positions each
    const int m    = lane & 15;
    const int q    = lane >> 4;

    const int p0 = blockIdx.x * 128;  // block: 128 consecutive positions
    const int b  = p0 >> 12;
    const int n0 = p0 & (VQ_HW - 1);
    const float* xw = x + (size_t)b * (VQ_D * VQ_HW) + n0 + wv * 32;

    const char* gs = (const char*)ws + lane * 16;   // per-lane stream cursor

    STAGE(gs, 0)                      // chunk 0 -> buf0 (hides under A build)

    // ---- A fragments: hi, 2048*hi (exact), scaled residual; 2 M-tiles ----
    f16x8 Ah[2][2], Ak[2][2], Ra[2][2];
    #pragma unroll
    for (int tl = 0; tl < 2; ++tl)
        #pragma unroll
        for (int ks = 0; ks < 2; ++ks) {
            f16x8 h8, k8, r8;
            #pragma unroll
            for (int j = 0; j < 8; ++j) {
                const float v = xw[(size_t)(ks * 32 + q * 8 + j) * VQ_HW + tl * 16 + m];
                const _Float16 vh = (_Float16)v;
                h8[j] = vh;
                k8[j] = (_Float16)((float)vh * 2048.0f);     // exact (pow2)
                r8[j] = (_Float16)((v - (float)vh) * SC);
            }
            Ah[tl][ks] = h8; Ak[tl][ks] = k8; Ra[tl][ks] = r8;
        }

    int d1[2][4], d2[2][4];
    #pragma unroll
    for (int tl = 0; tl < 2; ++tl)
        #pragma unroll
        for (int r = 0; r < 4; ++r) { d1[tl][r] = 0x7FFFFFFF; d2[tl][r] = 0x7FFFFFFF; }

    const char* lp = (const char*)bbuf + lane * 16;        // B/R reads
    const char* cp = (const char*)bbuf + 16384 + m * 4;    // cn_q reads

    for (int it8 = 0; it8 < 8; ++it8) {     // 2 chunks (8 cts) per iteration
        const int cg = it8 * 8;
        __syncthreads();                    // chunk 2*it8 ready in buf0
        STAGE(gs + CHB, CHBP)               // chunk 2*it8+1 -> buf1
        CT_BODY(0, 0, cg + 0)
        CT_BODY(0, 1, cg + 1)
        CT_BODY(0, 2, cg + 2)
        CT_BODY(0, 3, cg + 3)
        __syncthreads();                    // chunk 2*it8+1 ready in buf1
        if (it8 < 7) STAGE(gs + 2 * CHB, 0) // chunk 2*it8+2 -> buf0
        CT_BODY(CHBP, 0, cg + 4)
        CT_BODY(CHBP, 1, cg + 5)
        CT_BODY(CHBP, 2, cg + 6)
        CT_BODY(CHBP, 3, cg + 7)
        gs += 2 * CHB;
    }

    // ---- top-2 merge across the 16 code-columns (keys carry the code) ----
    #pragma unroll
    for (int off = 1; off < 16; off <<= 1)
        #pragma unroll
        for (int tl = 0; tl < 2; ++tl)
            #pragma unroll
            for (int r = 0; r < 4; ++r) {
                const int od1 = __shfl_xor(d1[tl][r], off, 64);
                const int od2 = __shfl_xor(d2[tl][r], off, 64);
                const int mx  = (d1[tl][r] > od1) ? d1[tl][r] : od1;
                const int mn2 = (d2[tl][r] < od2) ? d2[tl][r] : od2;
                d2[tl][r] = (mx < mn2) ? mx : mn2;
                d1[tl][r] = (d1[tl][r] < od1) ? d1[tl][r] : od1;
            }

    if (m == 0) {
        #pragma unroll
        for (int tl = 0; tl < 2; ++tl)
            #pragma unroll
            for (int r = 0; r < 4; ++r) {
                const int li = wv * 32 + tl * 16 + q * 4 + r;
                sk[li]  = d1[tl][r] & 1023;
                smg[li] = (d2[tl][r] >> 10) - (d1[tl][r] >> 10);   // gap, q-units
            }
    }
    __syncthreads();

    // ---- epilogue: indices, rescan flags, quantized scatter ----
    const int pos  = tid & 127;
    const int half = tid >> 7;        // 2 threads per position, 32 dims each
    const int bk   = sk[pos];
    if (half == 0) {
        idx_out[p0 + pos] = (float)bk;
        if (smg[pos] < EPS_Q) {
            const int slot = atomicAdd((int*)ws + WS_CNT, 1);
            ((int*)ws)[WS_LIST + slot] = p0 + pos;
        }
    }
    const float4* cr = (const float4*)(cb + (size_t)bk * VQ_D) + half * 8;
    float* ob = out + (size_t)b * (VQ_D * VQ_HW) + (size_t)(half * 32) * VQ_HW + n0 + pos;
    #pragma unroll
    for (int d4 = 0; d4 < 8; ++d4) {
        const float4 v = cr[d4];
        ob[(size_t)(d4 * 4 + 0) * VQ_HW] = v.x;
        ob[(size_t)(d4 * 4 + 1) * VQ_HW] = v.y;
        ob[(size_t)(d4 * 4 + 2) * VQ_HW] = v.z;
        ob[(size_t)(d4 * 4 + 3) * VQ_HW] = v.w;
    }
}

// ---------- rescan: exact f32 argmin for flagged positions (verified) ----------
__global__ __launch_bounds__(64)
void vq_rescan(const float* __restrict__ x,
               const float* __restrict__ cb,
               const float* __restrict__ ws,
               float* __restrict__ out,
               float* __restrict__ idx_out)
{
    __shared__ float xs[VQ_D];
    const int lane = threadIdx.x;
    const int cnt  = ((const int*)ws)[WS_CNT];
    const int* list = (const int*)ws + WS_LIST;
    const float*  cnb  = ws + WS_CBN;
    const float4* cbT4 = (const float4*)(ws + WS_CBT);

    for (int i = blockIdx.x; i < cnt; i += gridDim.x) {
        const int p = list[i];
        const int b = p >> 12, n = p & (VQ_HW - 1);
        xs[lane] = x[(size_t)b * (VQ_D * VQ_HW) + (size_t)lane * VQ_HW + n];
        __syncthreads();
        float4 xr[16];
        #pragma unroll
        for (int j = 0; j < 16; ++j) xr[j] = ((const float4*)xs)[j];

        float bd = 3.4e38f; int bk = 0;
        #pragma unroll 4
        for (int t = 0; t < 16; ++t) {
            const int code = t * 64 + lane;           // per-lane ascending
            float a0 = 0.f, a1 = 0.f, a2 = 0.f, a3 = 0.f;
            #pragma unroll
            for (int j4 = 0; j4 < 16; ++j4) {
                const float4 c = cbT4[j4 * 1024 + code];   // coalesced
                a0 = fmaf(xr[j4].x, c.x, a0); a1 = fmaf(xr[j4].y, c.y, a1);
                a2 = fmaf(xr[j4].z, c.z, a2); a3 = fmaf(xr[j4].w, c.w, a3);
            }
            const float dist = fmaf(-2.0f, (a0 + a1) + (a2 + a3), cnb[code]);
            if (dist < bd) { bd = dist; bk = code; }
        }
        #pragma unroll
        for (int off = 1; off < 64; off <<= 1) {      // min dist, tie -> min k
            const float od = __shfl_xor(bd, off, 64);
            const int   ok = __shfl_xor(bk, off, 64);
            if (od < bd || (od == bd && ok < bk)) { bd = od; bk = ok; }
        }
        out[(size_t)b * (VQ_D * VQ_HW) + (size_t)lane * VQ_HW + n] = cb[(size_t)bk * VQ_D + lane];
        if (lane == 0) idx_out[p] = (float)bk;
        __syncthreads();
    }
}

extern "C" void kernel_launch(void* const* d_in, const int* in_sizes, int n_in,
                              void* d_out, int out_size, void* d_ws, size_t ws_size,
                              hipStream_t stream) {
    const float* x  = (const float*)d_in[0];
    const float* cb = (const float*)d_in[1];
    float* out = (float*)d_out;
    float* idx = out + (size_t)VQ_NPOS * VQ_D;   // 8,388,608 floats in
    float* ws  = (float*)d_ws;                    // ~1.06 MB used

    vq_prep  <<<dim3(132),  dim3(256), 0, stream>>>(cb, ws);
    vq_main  <<<dim3(1024), dim3(256), 0, stream>>>(x, cb, ws, out, idx);
    vq_rescan<<<dim3(1024), dim3(64),  0, stream>>>(x, cb, ws, out, idx);
}